// Round 10
// baseline (280.928 us; speedup 1.0000x reference)
//
#include <hip/hip_runtime.h>
#include <hip/hip_bf16.h>

// Problem constants: B=4 S=8192 D=1024 K=1024, TAU=1.0
constexpr int MM   = 32768;    // B*S
constexpr int NN   = 1024;     // output cols of both GEMMs
constexpr int KRED = 1024;     // reduction dim
constexpr int LDAB = KRED * 2; // bytes per bf16 row of A / Bt

using s16x8 = __attribute__((ext_vector_type(8))) short;
using f32x4 = __attribute__((ext_vector_type(4))) float;

__device__ __forceinline__ unsigned short f2bf(float f) {
  unsigned u = __float_as_uint(f);
  return (unsigned short)((u + 0x7fffu + ((u >> 16) & 1u)) >> 16);
}

__device__ __forceinline__ void gload_lds16(const void* g, void* l) {
  __builtin_amdgcn_global_load_lds(
      (const __attribute__((address_space(1))) void*)g,
      (__attribute__((address_space(3))) void*)l, 16, 0, 0);
}

__device__ __forceinline__ float wave_sum(float v) {
#pragma unroll
  for (int o = 32; o > 0; o >>= 1) v += __shfl_xor(v, o);
  return v;
}

// ---------------------------------------------------------------------------
// prep_cb: CB (bf16 [K,D]), CT (bf16 [D,K]), c2[k] (f32 exact).
// ---------------------------------------------------------------------------
__global__ __launch_bounds__(256) void prep_cb(const float* __restrict__ C,
                                               unsigned short* __restrict__ CB,
                                               unsigned short* __restrict__ CT,
                                               float* __restrict__ c2) {
  int k = blockIdx.x;
  int t = threadIdx.x;
  const float4 v = *(const float4*)(C + (size_t)k * 1024 + t * 4);
  ushort4 b = make_ushort4(f2bf(v.x), f2bf(v.y), f2bf(v.z), f2bf(v.w));
  *(ushort4*)(CB + (size_t)k * 1024 + t * 4) = b;
  CT[(size_t)(t * 4 + 0) * 1024 + k] = b.x;
  CT[(size_t)(t * 4 + 1) * 1024 + k] = b.y;
  CT[(size_t)(t * 4 + 2) * 1024 + k] = b.z;
  CT[(size_t)(t * 4 + 3) * 1024 + k] = b.w;
  float p = v.x * v.x + v.y * v.y + v.z * v.z + v.w * v.w;
  p = wave_sum(p);
  __shared__ float red[4];
  if ((t & 63) == 0) red[t >> 6] = p;
  __syncthreads();
  if (t == 0) c2[k] = red[0] + red[1] + red[2] + red[3];
}

// ---------------------------------------------------------------------------
// prep_x: wave-per-row (proven R3). Xb (bf16 [M,D]), x2[m] (f32, exact).
// ---------------------------------------------------------------------------
__global__ __launch_bounds__(512) void prep_x(const float* __restrict__ X,
                                              unsigned short* __restrict__ Xb,
                                              float* __restrict__ x2) {
  int tid = threadIdx.x;
  int l = tid & 63, w = tid >> 6;
  int m = blockIdx.x * 8 + w;
  size_t base = (size_t)m * 1024 + l * 4;
  float p = 0.0f;
#pragma unroll
  for (int j = 0; j < 4; ++j) {
    const float4 v = *(const float4*)(X + base + j * 256);
    *(ushort4*)(Xb + base + j * 256) =
        make_ushort4(f2bf(v.x), f2bf(v.y), f2bf(v.z), f2bf(v.w));
    p += v.x * v.x + v.y * v.y + v.z * v.z + v.w * v.w;
  }
  p = wave_sum(p);
  if (l == 0) x2[m] = p;
}

// ---------------------------------------------------------------------------
// softmax (no-max variant, proven R9): wave-per-row, zero barriers.
// exp(gumbel) = 1/(-log u); p~ = exp(lg)*r, all f32-safe; W = p~/sum.
// ---------------------------------------------------------------------------
__global__ __launch_bounds__(512) void softmax_k(const float* __restrict__ logits,
                                                 const float* __restrict__ noise,
                                                 unsigned short* __restrict__ W) {
  int tid = threadIdx.x;
  int l = tid & 63, w = tid >> 6;
  int m = blockIdx.x * 8 + w;
  size_t base = (size_t)m * 1024 + l * 4;

  float p[16];
  float ps = 0.0f;
#pragma unroll
  for (int j = 0; j < 4; ++j) {
    const float4 lv = *(const float4*)(logits + base + j * 256);
    const float4 nv = *(const float4*)(noise + base + j * 256);
    p[j * 4 + 0] = __expf(lv.x) * (1.0f / (-__logf(nv.x)));
    p[j * 4 + 1] = __expf(lv.y) * (1.0f / (-__logf(nv.y)));
    p[j * 4 + 2] = __expf(lv.z) * (1.0f / (-__logf(nv.z)));
    p[j * 4 + 3] = __expf(lv.w) * (1.0f / (-__logf(nv.w)));
    ps += p[j * 4 + 0] + p[j * 4 + 1] + p[j * 4 + 2] + p[j * 4 + 3];
  }
  ps = wave_sum(ps);
  float inv = 1.0f / ps;

#pragma unroll
  for (int j = 0; j < 4; ++j) {
    *(ushort4*)(W + base + j * 256) =
        make_ushort4(f2bf(p[j * 4 + 0] * inv), f2bf(p[j * 4 + 1] * inv),
                     f2bf(p[j * 4 + 2] * inv), f2bf(p[j * 4 + 3] * inv));
  }
}

// ---------------------------------------------------------------------------
// gemm128<MODE>: m97-class 128x128 tile, BK=64, 4 waves (2x2, 64x64/wave),
// double-buffered 64 KiB LDS -> 2 blocks/CU (epilogue/prologue of one block
// overlaps the K-loop of the co-resident block — fixes the 1-blk/CU
// serialization diagnosed on the 256^2 kernel). Per K-tile: STAGE(t+1) into
// buf[1-p] (async, hides under MFMA), ds_read buf[p], 32 MFMA, single
// vmcnt(0)+barrier. XOR swizzle both sides (conflict-free, PMC-verified).
// MODE==1: epilogue v -> -sqrt(max(x2[row]+c2[col]-2v,0)).  MODE==0: plain.
// ---------------------------------------------------------------------------
template <int MODE>
__global__ __launch_bounds__(256, 2) void gemm128(const unsigned short* __restrict__ A,
                                                  const unsigned short* __restrict__ Bt,
                                                  float* __restrict__ out,
                                                  const float* __restrict__ x2,
                                                  const float* __restrict__ c2) {
  __shared__ __align__(16) char smem[65536];  // 2 bufs x (A 16K + B 16K)

  int bid = blockIdx.x;                      // 2048 blocks
  int swz = (bid & 7) * 256 + (bid >> 3);    // XCD swizzle (2048 % 8 == 0)
  int bm = swz >> 3, bn = swz & 7;           // 256 x 8
  int brow0 = bm * 128, bcol0 = bn * 128;

  int tid = threadIdx.x;
  int l = tid & 63, w = tid >> 6;            // 4 waves
  int wm = w >> 1, wn = w & 1;               // 2x2; per-wave 64x64
  int lr = l & 15, lh = l >> 4;
  const int xsw = (lr & 7) << 4;

  const char* Ab = (const char*)A + (size_t)brow0 * LDAB;
  const char* Bb = (const char*)Bt + (size_t)bcol0 * LDAB;

  // staging: thread covers row srow+i*32 (i=0..3), 16B col chunk (tid&7)*16,
  // source col inverse-swizzled so linear LDS dest + swizzled read match.
  const int srow = tid >> 3;                 // 0..31
  const int scx  = ((tid & 7) * 16) ^ ((srow & 7) << 4);

#define STAGE(buf, kbyte)                                                      \
  do {                                                                         \
    _Pragma("unroll")                                                          \
    for (int i = 0; i < 4; ++i) {                                              \
      gload_lds16(Ab + (size_t)(i * 32 + srow) * LDAB + (kbyte) + scx,         \
                  smem + (buf) * 32768 + i * 4096 + tid * 16);                 \
      gload_lds16(Bb + (size_t)(i * 32 + srow) * LDAB + (kbyte) + scx,         \
                  smem + (buf) * 32768 + 16384 + i * 4096 + tid * 16);         \
    }                                                                          \
  } while (0)

  // prologue: tile 0 -> buf 0
  STAGE(0, 0);
  asm volatile("s_waitcnt vmcnt(0)" ::: "memory");
  __builtin_amdgcn_s_barrier();

  const int aoff = wm * 8192 + lr * 128;     // byte offset of fragment row 0
  const int boff = wn * 8192 + lr * 128;

  f32x4 acc[4][4] = {};

  for (int t = 0; t < 16; ++t) {
    int p = t & 1;
    const char* As = smem + p * 32768;
    const char* Bs = smem + p * 32768 + 16384;

    if (t + 1 < 16) STAGE(1 - p, (t + 1) * 128);  // async, hides under MFMA

    s16x8 af[4][2], bf[4][2];
#pragma unroll
    for (int mi = 0; mi < 4; ++mi)
#pragma unroll
      for (int ks = 0; ks < 2; ++ks) {
        af[mi][ks] = *(const s16x8*)(As + aoff + mi * 2048 + ((ks * 64 + lh * 16) ^ xsw));
        bf[mi][ks] = *(const s16x8*)(Bs + boff + mi * 2048 + ((ks * 64 + lh * 16) ^ xsw));
      }
#pragma unroll
    for (int mi = 0; mi < 4; ++mi)
#pragma unroll
      for (int ni = 0; ni < 4; ++ni)
#pragma unroll
        for (int ks = 0; ks < 2; ++ks)
          acc[mi][ni] = __builtin_amdgcn_mfma_f32_16x16x32_bf16(af[mi][ks], bf[ni][ks], acc[mi][ni], 0, 0, 0);

    asm volatile("s_waitcnt vmcnt(0)" ::: "memory");  // next tile landed
    __builtin_amdgcn_s_barrier();                     // all reads+writes done
  }
#undef STAGE

  // epilogue: C/D layout col=lane&15, row=(lane>>4)*4+reg
#pragma unroll
  for (int mi = 0; mi < 4; ++mi) {
    int row0 = brow0 + wm * 64 + mi * 16 + lh * 4;
#pragma unroll
    for (int r = 0; r < 4; ++r) {
      int row = row0 + r;
      float xv = (MODE == 1) ? x2[row] : 0.0f;
#pragma unroll
      for (int ni = 0; ni < 4; ++ni) {
        int col = bcol0 + wn * 64 + ni * 16 + lr;
        float v = acc[mi][ni][r];
        if (MODE == 1) {
          float d2 = xv + c2[col] - 2.0f * v;
          v = -sqrtf(fmaxf(d2, 0.0f));
        }
        out[(size_t)row * NN + col] = v;
      }
    }
  }
}

// ---------------------------------------------------------------------------
extern "C" void kernel_launch(void* const* d_in, const int* in_sizes, int n_in,
                              void* d_out, int out_size, void* d_ws, size_t ws_size,
                              hipStream_t stream) {
  const float* emb   = (const float*)d_in[0];
  const float* cb    = (const float*)d_in[1];
  const float* noise = (const float*)d_in[2];

  float* quant  = (float*)d_out;
  float* logits = (float*)d_out + (size_t)MM * NN;

  char* ws = (char*)d_ws;
  unsigned short* XW = (unsigned short*)ws;               // 64 MiB X then W bf16
  unsigned short* CB = (unsigned short*)(ws + 67108864);  // 2 MiB
  unsigned short* CT = (unsigned short*)(ws + 69206016);  // 2 MiB
  float* x2 = (float*)(ws + 71303168);                    // 128 KiB
  float* c2 = (float*)(ws + 71434240);                    // 4 KiB

  prep_cb<<<dim3(1024), dim3(256), 0, stream>>>(cb, CB, CT, c2);
  prep_x<<<dim3(MM / 8), dim3(512), 0, stream>>>(emb, XW, x2);
  gemm128<1><<<dim3(2048), dim3(256), 0, stream>>>(XW, CB, logits, x2, c2);
  softmax_k<<<dim3(MM / 8), dim3(512), 0, stream>>>(logits, noise, XW);
  gemm128<0><<<dim3(2048), dim3(256), 0, stream>>>(XW, CT, quant, nullptr, nullptr);
}